// Round 15
// baseline (124.832 us; speedup 1.0000x reference)
//
#include <hip/hip_runtime.h>
#include <hip/hip_fp16.h>

typedef float    f32x4 __attribute__((ext_vector_type(4)));
typedef _Float16 f16x8 __attribute__((ext_vector_type(8)));

#define BF_DIM 1024
#define BF_STAGES 10

// f16 (cos,sin) tables: 4 B/pair, 2 KB/stage, 20 KB total -> L1-resident,
// shared by every block on a CU (same global addresses).
// Per stage, lane l's 8 needed pairs are packed contiguously at pairs [l*8..l*8+7]:
//   stages 0-3: pos = k (natural order IS lane-contiguous for the reg layout)
//   stages 4-7: k = hi2*128 + j*16 + lo4 -> pos = (hi2*16+lo4)*8 + j   (layout B)
//   stages 8-9: k = g*256 + lane*4 + c   -> pos = lane*8 + g*4 + c     (layout C)
__global__ void bf_fill_cs(const float* __restrict__ angles, unsigned* __restrict__ cs, int n) {
    int i = blockIdx.x * blockDim.x + threadIdx.x;
    if (i >= n) return;
    int s = i >> 9, k = i & 511;
    float a = angles[i];
    float sv, cv;
    sincosf(a, &sv, &cv);
    int pos;
    if (s >= 4 && s < 8) {
        int hi2 = k >> 7, j = (k >> 4) & 7, lo4 = k & 15;
        pos = ((hi2 << 4) | lo4) * 8 + j;
    } else if (s >= 8) {
        pos = ((k & 255) >> 2) * 8 + (k >> 8) * 4 + (k & 3);
    } else {
        pos = k;
    }
    unsigned hc = __half_as_ushort(__float2half_rn(cv));
    unsigned hs = __half_as_ushort(__float2half_rn(sv));
    cs[s * 512 + pos] = (hs << 16) | hc;   // low16 = cos, high16 = sin (LE)
}

#define ROT(vi, vj, c, s) do { float _t = fmaf(-(s), (vj), (c)*(vi)); \
                               (vj) = fmaf((s), (vi), (c)*(vj)); (vi) = _t; } while (0)

// Expand one f16x8 (4 cos/sin pairs) into two f32x4 coeff vecs (c0,s0,c1,s1).
#define EXP(t, ca, cb) do { \
    ca = (f32x4){(float)(t)[0], (float)(t)[1], (float)(t)[2], (float)(t)[3]}; \
    cb = (f32x4){(float)(t)[4], (float)(t)[5], (float)(t)[6], (float)(t)[7]}; } while (0)

// Half-stage ops on a pair of data vecs with 2 coeff vecs (4 pairs).
#define H_EVEN(P, Q, c0, c1) do { \
    ROT(P.x, P.y, c0.x, c0.y); ROT(P.z, P.w, c0.z, c0.w); \
    ROT(Q.x, Q.y, c1.x, c1.y); ROT(Q.z, Q.w, c1.z, c1.w); } while (0)
#define H_ODD(P, Q, c0, c1) do { \
    ROT(P.x, P.z, c0.x, c0.y); ROT(P.y, P.w, c0.z, c0.w); \
    ROT(Q.x, Q.z, c1.x, c1.y); ROT(Q.y, Q.w, c1.z, c1.w); } while (0)
#define H_PAIR(P, Q, c0, c1) do { \
    ROT(P.x, Q.x, c0.x, c0.y); ROT(P.y, Q.y, c0.z, c0.w); \
    ROT(P.z, Q.z, c1.x, c1.y); ROT(P.w, Q.w, c1.z, c1.w); } while (0)

// One full stage = two in-loop f16x8 L1-hit loads (r9 scheme); expand lazily.
#define DO_STAGE(HOP, sidx, X0, X1, X2, X3, Y0, Y1, Y2, Y3) do { \
    f16x8 _t0 = TH[(sidx) * 128 + lane * 2], _t1 = TH[(sidx) * 128 + lane * 2 + 1]; \
    f32x4 _c0, _c1; \
    EXP(_t0, _c0, _c1); \
    HOP(X0, X1, _c0, _c1); HOP(Y0, Y1, _c0, _c1); \
    EXP(_t1, _c0, _c1); \
    HOP(X2, X3, _c0, _c1); HOP(Y2, Y3, _c0, _c1); } while (0)

// Round-15 = r14 (106.5us: plain accesses, R=2, f16 tables, single 5KB slab,
// 32 waves/CU, zero barriers) with a split nt policy:
//   - data LOADS:  nt (read-once stream; nt marks lines low-priority so the
//     8KB/pair input stream does NOT evict the 20KB L1-resident table)
//   - data STORES: plain (r14 proved nt stores were a flat ~20% BW tax)
// This separates the two effects r14 changed together.
__global__ __launch_bounds__(256) void bf_butterfly(const float* __restrict__ x,
                                                    const f16x8* __restrict__ TH,
                                                    float* __restrict__ out,
                                                    int n_rows, int pair_stride) {
    __shared__ __align__(16) float lds[4 * 1280];  // 4 waves * 1280 words = 20 KB
    const int lane = threadIdx.x & 63;
    const int wv   = threadIdx.x >> 6;
    float* L = lds + wv * 1280;

    const int wb = lane * 20;                         // layout A base
    const int rb = (lane >> 4) * 320 + (lane & 15);   // layout B base
    const int cb = (lane >> 2) * 20 + (lane & 3) * 4; // layout C base

    const int n_pairs = (n_rows + 1) >> 1;

#pragma unroll 1
    for (int pair = blockIdx.x * 4 + wv; pair < n_pairs; pair += pair_stride) {
        const int r0 = pair * 2;
        const int r1 = r0 + 1;
        const bool has1 = (r1 < n_rows);

        const float* xr0 = x + (long long)r0 * BF_DIM + lane * 16;
        const float* xr1 = x + (long long)(has1 ? r1 : r0) * BF_DIM + lane * 16;
        f32x4 U0 = __builtin_nontemporal_load((const f32x4*)(xr0 + 0));
        f32x4 U1 = __builtin_nontemporal_load((const f32x4*)(xr0 + 4));
        f32x4 U2 = __builtin_nontemporal_load((const f32x4*)(xr0 + 8));
        f32x4 U3 = __builtin_nontemporal_load((const f32x4*)(xr0 + 12));
        f32x4 W0 = __builtin_nontemporal_load((const f32x4*)(xr1 + 0));
        f32x4 W1 = __builtin_nontemporal_load((const f32x4*)(xr1 + 4));
        f32x4 W2 = __builtin_nontemporal_load((const f32x4*)(xr1 + 8));
        f32x4 W3 = __builtin_nontemporal_load((const f32x4*)(xr1 + 12));

        // ---- stages 0-3 (layout A, in regs; tables shared by both rows)
        DO_STAGE(H_EVEN, 0, U0, U1, U2, U3, W0, W1, W2, W3);
        DO_STAGE(H_ODD,  1, U0, U1, U2, U3, W0, W1, W2, W3);
        DO_STAGE(H_PAIR, 2, U0, U1, U2, U3, W0, W1, W2, W3);
        DO_STAGE(H_PAIR, 3, U0, U2, U1, U3, W0, W2, W1, W3);  // pairs (0,2),(1,3)

        // ---- transpose 1 through the single slab, row0 then row1.
        // In-order DS pipe: U's b32 reads are issued (and complete) before
        // W's b128 writes touch the same words -> no barrier needed.
        *(f32x4*)(L + wb + 0)  = U0;
        *(f32x4*)(L + wb + 4)  = U1;
        *(f32x4*)(L + wb + 8)  = U2;
        *(f32x4*)(L + wb + 12) = U3;
        U0.x = L[rb + 0 * 20];  U0.y = L[rb + 1 * 20];  U0.z = L[rb + 2 * 20];  U0.w = L[rb + 3 * 20];
        U1.x = L[rb + 4 * 20];  U1.y = L[rb + 5 * 20];  U1.z = L[rb + 6 * 20];  U1.w = L[rb + 7 * 20];
        U2.x = L[rb + 8 * 20];  U2.y = L[rb + 9 * 20];  U2.z = L[rb + 10 * 20]; U2.w = L[rb + 11 * 20];
        U3.x = L[rb + 12 * 20]; U3.y = L[rb + 13 * 20]; U3.z = L[rb + 14 * 20]; U3.w = L[rb + 15 * 20];
        *(f32x4*)(L + wb + 0)  = W0;
        *(f32x4*)(L + wb + 4)  = W1;
        *(f32x4*)(L + wb + 8)  = W2;
        *(f32x4*)(L + wb + 12) = W3;
        W0.x = L[rb + 0 * 20];  W0.y = L[rb + 1 * 20];  W0.z = L[rb + 2 * 20];  W0.w = L[rb + 3 * 20];
        W1.x = L[rb + 4 * 20];  W1.y = L[rb + 5 * 20];  W1.z = L[rb + 6 * 20];  W1.w = L[rb + 7 * 20];
        W2.x = L[rb + 8 * 20];  W2.y = L[rb + 9 * 20];  W2.z = L[rb + 10 * 20]; W2.w = L[rb + 11 * 20];
        W3.x = L[rb + 12 * 20]; W3.y = L[rb + 13 * 20]; W3.z = L[rb + 14 * 20]; W3.w = L[rb + 15 * 20];

        // ---- stages 4-7 (layout B, in regs)
        DO_STAGE(H_EVEN, 4, U0, U1, U2, U3, W0, W1, W2, W3);
        DO_STAGE(H_ODD,  5, U0, U1, U2, U3, W0, W1, W2, W3);
        DO_STAGE(H_PAIR, 6, U0, U1, U2, U3, W0, W1, W2, W3);
        DO_STAGE(H_PAIR, 7, U0, U2, U1, U3, W0, W2, W1, W3);

        // ---- transpose 2 through the single slab, row0 then row1.
        L[rb + 0 * 20]  = U0.x; L[rb + 1 * 20]  = U0.y; L[rb + 2 * 20]  = U0.z; L[rb + 3 * 20]  = U0.w;
        L[rb + 4 * 20]  = U1.x; L[rb + 5 * 20]  = U1.y; L[rb + 6 * 20]  = U1.z; L[rb + 7 * 20]  = U1.w;
        L[rb + 8 * 20]  = U2.x; L[rb + 9 * 20]  = U2.y; L[rb + 10 * 20] = U2.z; L[rb + 11 * 20] = U2.w;
        L[rb + 12 * 20] = U3.x; L[rb + 13 * 20] = U3.y; L[rb + 14 * 20] = U3.z; L[rb + 15 * 20] = U3.w;
        U0 = *(const f32x4*)(L + cb);
        U1 = *(const f32x4*)(L + cb + 320);
        U2 = *(const f32x4*)(L + cb + 640);
        U3 = *(const f32x4*)(L + cb + 960);
        L[rb + 0 * 20]  = W0.x; L[rb + 1 * 20]  = W0.y; L[rb + 2 * 20]  = W0.z; L[rb + 3 * 20]  = W0.w;
        L[rb + 4 * 20]  = W1.x; L[rb + 5 * 20]  = W1.y; L[rb + 6 * 20]  = W1.z; L[rb + 7 * 20]  = W1.w;
        L[rb + 8 * 20]  = W2.x; L[rb + 9 * 20]  = W2.y; L[rb + 10 * 20] = W2.z; L[rb + 11 * 20] = W2.w;
        L[rb + 12 * 20] = W3.x; L[rb + 13 * 20] = W3.y; L[rb + 14 * 20] = W3.z; L[rb + 15 * 20] = W3.w;
        W0 = *(const f32x4*)(L + cb);
        W1 = *(const f32x4*)(L + cb + 320);
        W2 = *(const f32x4*)(L + cb + 640);
        W3 = *(const f32x4*)(L + cb + 960);

        // ---- stages 8-9 (layout C, in regs)
        DO_STAGE(H_PAIR, 8, U0, U1, U2, U3, W0, W1, W2, W3);
        DO_STAGE(H_PAIR, 9, U0, U2, U1, U3, W0, W2, W1, W3);

        float* o0 = out + (long long)r0 * BF_DIM;
        *(f32x4*)(o0 + lane * 4)       = U0;
        *(f32x4*)(o0 + 256 + lane * 4) = U1;
        *(f32x4*)(o0 + 512 + lane * 4) = U2;
        *(f32x4*)(o0 + 768 + lane * 4) = U3;
        if (has1) {
            float* o1 = out + (long long)r1 * BF_DIM;
            *(f32x4*)(o1 + lane * 4)       = W0;
            *(f32x4*)(o1 + 256 + lane * 4) = W1;
            *(f32x4*)(o1 + 512 + lane * 4) = W2;
            *(f32x4*)(o1 + 768 + lane * 4) = W3;
        }
    }
}

extern "C" void kernel_launch(void* const* d_in, const int* in_sizes, int n_in,
                              void* d_out, int out_size, void* d_ws, size_t ws_size,
                              hipStream_t stream) {
    const float* x      = (const float*)d_in[0];
    const float* angles = (const float*)d_in[1];
    float*       out    = (float*)d_out;
    unsigned*    cs     = (unsigned*)d_ws;  // 10*512*4 = 20480 bytes

    const int ncs = BF_STAGES * (BF_DIM / 2);
    bf_fill_cs<<<(ncs + 255) / 256, 256, 0, stream>>>(angles, cs, ncs);

    const int rows    = in_sizes[0] / BF_DIM;
    const int n_pairs = (rows + 1) / 2;
    int blocks = (n_pairs + 3) / 4;
    if (blocks > 2048) blocks = 2048;     // 8 blocks/CU (20KB LDS) -> 32 waves/CU
    const int pair_stride = blocks * 4;   // total waves
    bf_butterfly<<<blocks, 256, 0, stream>>>(x, (const f16x8*)cs, out, rows, pair_stride);
}

// Round 16
// 89.809 us; speedup vs baseline: 1.3900x; 1.3900x over previous
//
#include <hip/hip_runtime.h>
#include <hip/hip_fp16.h>

typedef float    f32x4 __attribute__((ext_vector_type(4)));
typedef _Float16 f16x8 __attribute__((ext_vector_type(8)));

#define BF_DIM 1024
#define BF_STAGES 10

// f16 (cos,sin) tables: 4 B/pair, 2 KB/stage, 20 KB total -> L1-resident,
// shared by every block on a CU (same global addresses).
// Per stage, lane l's 8 needed pairs are packed contiguously at pairs [l*8..l*8+7]:
//   stages 0-3: pos = k (natural order IS lane-contiguous for the reg layout)
//   stages 4-7: k = hi2*128 + j*16 + lo4 -> pos = (hi2*16+lo4)*8 + j   (layout B)
//   stages 8-9: k = g*256 + lane*4 + c   -> pos = lane*8 + g*4 + c     (layout C)
__global__ void bf_fill_cs(const float* __restrict__ angles, unsigned* __restrict__ cs, int n) {
    int i = blockIdx.x * blockDim.x + threadIdx.x;
    if (i >= n) return;
    int s = i >> 9, k = i & 511;
    float a = angles[i];
    float sv, cv;
    sincosf(a, &sv, &cv);
    int pos;
    if (s >= 4 && s < 8) {
        int hi2 = k >> 7, j = (k >> 4) & 7, lo4 = k & 15;
        pos = ((hi2 << 4) | lo4) * 8 + j;
    } else if (s >= 8) {
        pos = ((k & 255) >> 2) * 8 + (k >> 8) * 4 + (k & 3);
    } else {
        pos = k;
    }
    unsigned hc = __half_as_ushort(__float2half_rn(cv));
    unsigned hs = __half_as_ushort(__float2half_rn(sv));
    cs[s * 512 + pos] = (hs << 16) | hc;   // low16 = cos, high16 = sin (LE)
}

#define ROT(vi, vj, c, s) do { float _t = fmaf(-(s), (vj), (c)*(vi)); \
                               (vj) = fmaf((s), (vi), (c)*(vj)); (vi) = _t; } while (0)

// Expand one f16x8 (4 cos/sin pairs) into two f32x4 coeff vecs (c0,s0,c1,s1).
#define EXP(t, ca, cb) do { \
    ca = (f32x4){(float)(t)[0], (float)(t)[1], (float)(t)[2], (float)(t)[3]}; \
    cb = (f32x4){(float)(t)[4], (float)(t)[5], (float)(t)[6], (float)(t)[7]}; } while (0)

// Half-stage ops on a pair of data vecs with 2 coeff vecs (4 pairs).
#define H_EVEN(P, Q, c0, c1) do { \
    ROT(P.x, P.y, c0.x, c0.y); ROT(P.z, P.w, c0.z, c0.w); \
    ROT(Q.x, Q.y, c1.x, c1.y); ROT(Q.z, Q.w, c1.z, c1.w); } while (0)
#define H_ODD(P, Q, c0, c1) do { \
    ROT(P.x, P.z, c0.x, c0.y); ROT(P.y, P.w, c0.z, c0.w); \
    ROT(Q.x, Q.z, c1.x, c1.y); ROT(Q.y, Q.w, c1.z, c1.w); } while (0)
#define H_PAIR(P, Q, c0, c1) do { \
    ROT(P.x, Q.x, c0.x, c0.y); ROT(P.y, Q.y, c0.z, c0.w); \
    ROT(P.z, Q.z, c1.x, c1.y); ROT(P.w, Q.w, c1.z, c1.w); } while (0)

// One full stage = two in-loop f16x8 L1-hit loads (r9 scheme); expand lazily.
#define DO_STAGE(HOP, sidx, X0, X1, X2, X3, Y0, Y1, Y2, Y3) do { \
    f16x8 _t0 = TH[(sidx) * 128 + lane * 2], _t1 = TH[(sidx) * 128 + lane * 2 + 1]; \
    f32x4 _c0, _c1; \
    EXP(_t0, _c0, _c1); \
    HOP(X0, X1, _c0, _c1); HOP(Y0, Y1, _c0, _c1); \
    EXP(_t1, _c0, _c1); \
    HOP(X2, X3, _c0, _c1); HOP(Y2, Y3, _c0, _c1); } while (0)

// Round-16: fourth quadrant of the nt matrix. Measured so far:
//   {nt-load, nt-store} = 125us (r13)   {plain, plain}      = 106.5us (r14)
//   {nt-load, plain-st} = 124.8us (r15) {plain-ld, nt-st}   = THIS
// nt LOADS are the proven ~18us tax (r15). nt stores were ~free alongside
// nt loads (r13~r15); with plain loads they may WIN: the output stream is
// write-once-never-read, and nt stores skip L2/L3 write-allocate, leaving
// cache fill bandwidth and capacity to the read stream.
__global__ __launch_bounds__(256) void bf_butterfly(const float* __restrict__ x,
                                                    const f16x8* __restrict__ TH,
                                                    float* __restrict__ out,
                                                    int n_rows, int pair_stride) {
    __shared__ __align__(16) float lds[4 * 1280];  // 4 waves * 1280 words = 20 KB
    const int lane = threadIdx.x & 63;
    const int wv   = threadIdx.x >> 6;
    float* L = lds + wv * 1280;

    const int wb = lane * 20;                         // layout A base
    const int rb = (lane >> 4) * 320 + (lane & 15);   // layout B base
    const int cb = (lane >> 2) * 20 + (lane & 3) * 4; // layout C base

    const int n_pairs = (n_rows + 1) >> 1;

#pragma unroll 1
    for (int pair = blockIdx.x * 4 + wv; pair < n_pairs; pair += pair_stride) {
        const int r0 = pair * 2;
        const int r1 = r0 + 1;
        const bool has1 = (r1 < n_rows);

        const float* xr0 = x + (long long)r0 * BF_DIM + lane * 16;
        const float* xr1 = x + (long long)(has1 ? r1 : r0) * BF_DIM + lane * 16;
        f32x4 U0 = *(const f32x4*)(xr0 + 0);
        f32x4 U1 = *(const f32x4*)(xr0 + 4);
        f32x4 U2 = *(const f32x4*)(xr0 + 8);
        f32x4 U3 = *(const f32x4*)(xr0 + 12);
        f32x4 W0 = *(const f32x4*)(xr1 + 0);
        f32x4 W1 = *(const f32x4*)(xr1 + 4);
        f32x4 W2 = *(const f32x4*)(xr1 + 8);
        f32x4 W3 = *(const f32x4*)(xr1 + 12);

        // ---- stages 0-3 (layout A, in regs; tables shared by both rows)
        DO_STAGE(H_EVEN, 0, U0, U1, U2, U3, W0, W1, W2, W3);
        DO_STAGE(H_ODD,  1, U0, U1, U2, U3, W0, W1, W2, W3);
        DO_STAGE(H_PAIR, 2, U0, U1, U2, U3, W0, W1, W2, W3);
        DO_STAGE(H_PAIR, 3, U0, U2, U1, U3, W0, W2, W1, W3);  // pairs (0,2),(1,3)

        // ---- transpose 1 through the single slab, row0 then row1.
        // In-order DS pipe: U's b32 reads are issued (and complete) before
        // W's b128 writes touch the same words -> no barrier needed.
        *(f32x4*)(L + wb + 0)  = U0;
        *(f32x4*)(L + wb + 4)  = U1;
        *(f32x4*)(L + wb + 8)  = U2;
        *(f32x4*)(L + wb + 12) = U3;
        U0.x = L[rb + 0 * 20];  U0.y = L[rb + 1 * 20];  U0.z = L[rb + 2 * 20];  U0.w = L[rb + 3 * 20];
        U1.x = L[rb + 4 * 20];  U1.y = L[rb + 5 * 20];  U1.z = L[rb + 6 * 20];  U1.w = L[rb + 7 * 20];
        U2.x = L[rb + 8 * 20];  U2.y = L[rb + 9 * 20];  U2.z = L[rb + 10 * 20]; U2.w = L[rb + 11 * 20];
        U3.x = L[rb + 12 * 20]; U3.y = L[rb + 13 * 20]; U3.z = L[rb + 14 * 20]; U3.w = L[rb + 15 * 20];
        *(f32x4*)(L + wb + 0)  = W0;
        *(f32x4*)(L + wb + 4)  = W1;
        *(f32x4*)(L + wb + 8)  = W2;
        *(f32x4*)(L + wb + 12) = W3;
        W0.x = L[rb + 0 * 20];  W0.y = L[rb + 1 * 20];  W0.z = L[rb + 2 * 20];  W0.w = L[rb + 3 * 20];
        W1.x = L[rb + 4 * 20];  W1.y = L[rb + 5 * 20];  W1.z = L[rb + 6 * 20];  W1.w = L[rb + 7 * 20];
        W2.x = L[rb + 8 * 20];  W2.y = L[rb + 9 * 20];  W2.z = L[rb + 10 * 20]; W2.w = L[rb + 11 * 20];
        W3.x = L[rb + 12 * 20]; W3.y = L[rb + 13 * 20]; W3.z = L[rb + 14 * 20]; W3.w = L[rb + 15 * 20];

        // ---- stages 4-7 (layout B, in regs)
        DO_STAGE(H_EVEN, 4, U0, U1, U2, U3, W0, W1, W2, W3);
        DO_STAGE(H_ODD,  5, U0, U1, U2, U3, W0, W1, W2, W3);
        DO_STAGE(H_PAIR, 6, U0, U1, U2, U3, W0, W1, W2, W3);
        DO_STAGE(H_PAIR, 7, U0, U2, U1, U3, W0, W2, W1, W3);

        // ---- transpose 2 through the single slab, row0 then row1.
        L[rb + 0 * 20]  = U0.x; L[rb + 1 * 20]  = U0.y; L[rb + 2 * 20]  = U0.z; L[rb + 3 * 20]  = U0.w;
        L[rb + 4 * 20]  = U1.x; L[rb + 5 * 20]  = U1.y; L[rb + 6 * 20]  = U1.z; L[rb + 7 * 20]  = U1.w;
        L[rb + 8 * 20]  = U2.x; L[rb + 9 * 20]  = U2.y; L[rb + 10 * 20] = U2.z; L[rb + 11 * 20] = U2.w;
        L[rb + 12 * 20] = U3.x; L[rb + 13 * 20] = U3.y; L[rb + 14 * 20] = U3.z; L[rb + 15 * 20] = U3.w;
        U0 = *(const f32x4*)(L + cb);
        U1 = *(const f32x4*)(L + cb + 320);
        U2 = *(const f32x4*)(L + cb + 640);
        U3 = *(const f32x4*)(L + cb + 960);
        L[rb + 0 * 20]  = W0.x; L[rb + 1 * 20]  = W0.y; L[rb + 2 * 20]  = W0.z; L[rb + 3 * 20]  = W0.w;
        L[rb + 4 * 20]  = W1.x; L[rb + 5 * 20]  = W1.y; L[rb + 6 * 20]  = W1.z; L[rb + 7 * 20]  = W1.w;
        L[rb + 8 * 20]  = W2.x; L[rb + 9 * 20]  = W2.y; L[rb + 10 * 20] = W2.z; L[rb + 11 * 20] = W2.w;
        L[rb + 12 * 20] = W3.x; L[rb + 13 * 20] = W3.y; L[rb + 14 * 20] = W3.z; L[rb + 15 * 20] = W3.w;
        W0 = *(const f32x4*)(L + cb);
        W1 = *(const f32x4*)(L + cb + 320);
        W2 = *(const f32x4*)(L + cb + 640);
        W3 = *(const f32x4*)(L + cb + 960);

        // ---- stages 8-9 (layout C, in regs)
        DO_STAGE(H_PAIR, 8, U0, U1, U2, U3, W0, W1, W2, W3);
        DO_STAGE(H_PAIR, 9, U0, U2, U1, U3, W0, W2, W1, W3);

        float* o0 = out + (long long)r0 * BF_DIM;
        __builtin_nontemporal_store(U0, (f32x4*)(o0 + lane * 4));
        __builtin_nontemporal_store(U1, (f32x4*)(o0 + 256 + lane * 4));
        __builtin_nontemporal_store(U2, (f32x4*)(o0 + 512 + lane * 4));
        __builtin_nontemporal_store(U3, (f32x4*)(o0 + 768 + lane * 4));
        if (has1) {
            float* o1 = out + (long long)r1 * BF_DIM;
            __builtin_nontemporal_store(W0, (f32x4*)(o1 + lane * 4));
            __builtin_nontemporal_store(W1, (f32x4*)(o1 + 256 + lane * 4));
            __builtin_nontemporal_store(W2, (f32x4*)(o1 + 512 + lane * 4));
            __builtin_nontemporal_store(W3, (f32x4*)(o1 + 768 + lane * 4));
        }
    }
}

extern "C" void kernel_launch(void* const* d_in, const int* in_sizes, int n_in,
                              void* d_out, int out_size, void* d_ws, size_t ws_size,
                              hipStream_t stream) {
    const float* x      = (const float*)d_in[0];
    const float* angles = (const float*)d_in[1];
    float*       out    = (float*)d_out;
    unsigned*    cs     = (unsigned*)d_ws;  // 10*512*4 = 20480 bytes

    const int ncs = BF_STAGES * (BF_DIM / 2);
    bf_fill_cs<<<(ncs + 255) / 256, 256, 0, stream>>>(angles, cs, ncs);

    const int rows    = in_sizes[0] / BF_DIM;
    const int n_pairs = (rows + 1) / 2;
    int blocks = (n_pairs + 3) / 4;
    if (blocks > 2048) blocks = 2048;     // 8 blocks/CU (20KB LDS) -> 32 waves/CU
    const int pair_stride = blocks * 4;   // total waves
    bf_butterfly<<<blocks, 256, 0, stream>>>(x, (const f16x8*)cs, out, rows, pair_stride);
}